// Round 17
// baseline (271.199 us; speedup 1.0000x reference)
//
#include <hip/hip_runtime.h>
#include <stdint.h>

typedef unsigned short u16;
typedef float f32x4 __attribute__((ext_vector_type(4)));
typedef __bf16 bf16x8 __attribute__((ext_vector_type(8)));

static __device__ __forceinline__ u16 f2bf(float f) {
  union { float f; unsigned u; } v; v.f = f;
  unsigned r = v.u + 0x7fffu + ((v.u >> 16) & 1u);   // RNE
  return (u16)(r >> 16);
}
static __device__ __forceinline__ float bf2f(u16 h) {
  union { unsigned u; float f; } v; v.u = ((unsigned)h) << 16;
  return v.f;
}

#define GLD_LDS16(gp, lp) __builtin_amdgcn_global_load_lds( \
    (__attribute__((address_space(1))) void*)(gp),          \
    (__attribute__((address_space(3))) void*)(lp), 16, 0, 0)

#define MFMA16(a, b, c) __builtin_amdgcn_mfma_f32_16x16x32_bf16((a), (b), (c), 0, 0, 0)

// ---------------------------------------------- merged prep: conv + 5 transposes
__global__ void prep_kernel(const float* __restrict__ x, u16* __restrict__ xb,
                            const float* __restrict__ w_q, u16* __restrict__ wqT,
                            const float* __restrict__ w_kvd, u16* __restrict__ wkdT,
                            const float* __restrict__ w_ku, u16* __restrict__ wkuT,
                            const float* __restrict__ w_vu, u16* __restrict__ wvuT,
                            const float* __restrict__ w_o, u16* __restrict__ woT) {
  __shared__ float tile[32][33];
  const int bid = blockIdx.x;
  const int tx = threadIdx.x, ty = threadIdx.y;
  if (bid < 2048) {
    const int tid = ty * 32 + tx;
    const long n = 4096ll * 2048;
    const long stride = 2048ll * 256 * 4;
    for (long i = ((long)bid * 256 + tid) * 4; i < n; i += stride) {
      float4 v = *(const float4*)(x + i);
      union { u16 s[4]; uint2 u; } pk;
      pk.s[0] = f2bf(v.x); pk.s[1] = f2bf(v.y); pk.s[2] = f2bf(v.z); pk.s[3] = f2bf(v.w);
      *(uint2*)(xb + i) = pk.u;
    }
    return;
  }
  const float* W; u16* WT; int K, N, bx, by;
  int r = bid - 2048;
  if (r < 6144)        { W = w_q;   WT = wqT;  K = 2048; N = 3072; bx = r % 96; by = r / 96; }
  else if ((r -= 6144) < 512) { W = w_kvd; WT = wkdT; K = 2048; N = 256;  bx = r % 8;  by = r / 8; }
  else if ((r -= 512) < 768)  { W = w_ku;  WT = wkuT; K = 256;  N = 3072; bx = r % 96; by = r / 96; }
  else if ((r -= 768) < 512)  { W = w_vu;  WT = wvuT; K = 256;  N = 2048; bx = r % 64; by = r / 64; }
  else                 { r -= 512; W = w_o; WT = woT; K = 2048; N = 2048; bx = r % 64; by = r / 64; }
  const int n0 = bx * 32, k0 = by * 32;
#pragma unroll
  for (int i = 0; i < 32; i += 8) tile[ty + i][tx] = W[(long)(k0 + ty + i) * N + n0 + tx];
  __syncthreads();
#pragma unroll
  for (int i = 0; i < 32; i += 8)
    WT[(long)(n0 + ty + i) * K + k0 + tx] = f2bf(tile[tx][ty + i]);
}

// ------------------- fused-rope epilogue helper (q/k layout [row][h*192+d])
__device__ __forceinline__ void epilogue_rope_store(
    u16* __restrict__ C, const int N, const f32x4 (*acc)[4],
    const int m0, const int wr, const int wc, const int cbase_wave,
    const int lrow, const int lg, const bool ropewin,
    const float* __restrict__ freqs, const int sp) {
#pragma unroll
  for (int mi = 0; mi < 4; mi++) {
    const int r0 = m0 + (wr << 6) + (mi << 4) + (lg << 2);
#pragma unroll
    for (int r = 0; r < 4; r++) {
      float v0 = acc[mi][0][r], v1 = acc[mi][1][r];
      float v2 = acc[mi][2][r], v3 = acc[mi][3][r];
      if (ropewin) {
        const int t = (r0 + r) & 2047;
        const float2 cs0 = *(const float2*)&freqs[((long)(sp + t) * 32 + lrow) * 2];
        const float2 cs1 = *(const float2*)&freqs[((long)(sp + t) * 32 + 16 + lrow) * 2];
        const float n0v = v0 * cs0.x - v2 * cs0.y;
        const float n1v = v1 * cs1.x - v3 * cs1.y;
        const float n2v = v2 * cs0.x + v0 * cs0.y;
        const float n3v = v3 * cs1.x + v1 * cs1.y;
        v0 = n0v; v1 = n1v; v2 = n2v; v3 = n3v;
      }
      const long ro = (long)(r0 + r) * N + cbase_wave + lrow;
      C[ro] = f2bf(v0);
      C[ro + 16] = f2bf(v1);
      C[ro + 32] = f2bf(v2);
      C[ro + 48] = f2bf(v3);
    }
  }
}

// --------------------------------------- fused q + kv_down GEMM (shared A=xb)
__global__ __launch_bounds__(256, 2)
void gemm_q_kvd_kernel(const u16* __restrict__ A, const u16* __restrict__ wqT,
                       const u16* __restrict__ wkdT, u16* __restrict__ qb,
                       u16* __restrict__ kvb,
                       const float* __restrict__ freqs, const int* __restrict__ sp_ptr) {
  constexpr int K = 2048;
  const int bid = blockIdx.x;
  const int xcd = bid & 7;
  const int idx = bid >> 3;                 // 0..103
  const int m0 = ((xcd << 2) + (idx & 3)) << 7;
  const int n0raw = (idx >> 2) << 7;        // n-tile 0..25
  const bool is_kv = n0raw >= 3072;
  const u16* BT = is_kv ? (wkdT + (long)(n0raw - 3072) * K) : (wqT + (long)n0raw * K);
  u16* C = is_kv ? kvb : qb;
  const int N = is_kv ? 256 : 3072;
  const int c_base = is_kv ? (n0raw - 3072) : n0raw;
  __shared__ alignas(16) u16 lA[128 * 64];
  __shared__ alignas(16) u16 lB[128 * 64];
  const int tid = threadIdx.x;
  const int w = tid >> 6, l = tid & 63;
  const int wr = w >> 1, wc = w & 1;
  const int lrow = l & 15, lg = l >> 4;
  const int srow = l >> 3, scol = (l & 7) << 3;
  f32x4 acc[4][4] = {};
  for (int kt = 0; kt < K; kt += 64) {
    __syncthreads();
#pragma unroll
    for (int i = 0; i < 4; i++) {
      const int chunk = (w << 2) + i;
      const int row = (chunk << 3) + srow;
      GLD_LDS16(A + (long)(m0 + row) * K + kt + scol, &lA[chunk << 9]);
      GLD_LDS16(BT + (long)row * K + kt + scol, &lB[chunk << 9]);
    }
    __syncthreads();
#pragma unroll
    for (int kk = 0; kk < 2; kk++) {
      bf16x8 af[4], bb[4];
#pragma unroll
      for (int i = 0; i < 4; i++) {
        af[i] = *(const bf16x8*)&lA[((wr << 6) + (i << 4) + lrow) * 64 + (kk << 5) + (lg << 3)];
        bb[i] = *(const bf16x8*)&lB[((wc << 6) + (i << 4) + lrow) * 64 + (kk << 5) + (lg << 3)];
      }
#pragma unroll
      for (int mi = 0; mi < 4; mi++)
#pragma unroll
        for (int ni = 0; ni < 4; ni++)
          acc[mi][ni] = MFMA16(af[mi], bb[ni], acc[mi][ni]);
    }
  }
  const int cbase_wave = c_base + (wc << 6);
  const bool ropewin = (!is_kv) && (cbase_wave % 192 == 128);
  const int sp = sp_ptr[0];
  epilogue_rope_store(C, N, acc, m0, wr, wc, cbase_wave, lrow, lg, ropewin, freqs, sp);
}

// ---------------------------- merged k_up + vT GEMM (both K=256, read kvb)
__global__ __launch_bounds__(256, 2)
void gemm_kup_vt_kernel(const u16* __restrict__ kvb, const u16* __restrict__ wkuT,
                        const u16* __restrict__ wvuT, u16* __restrict__ kb,
                        u16* __restrict__ vTb,
                        const float* __restrict__ freqs, const int* __restrict__ sp_ptr) {
  constexpr int K = 256;
  const int bid = blockIdx.x;
  const u16 *A, *BT;
  u16* C;
  int N, m0, n0;
  bool is_k;
  if (bid < 768) {                          // k-up: 32 m-tiles x 24 n-tiles
    const int xcd = bid & 7, idx = bid >> 3;
    A = kvb; BT = wkuT; C = kb; N = 3072;
    m0 = ((xcd << 2) + (idx & 3)) << 7;
    n0 = (idx >> 2) << 7;
    is_k = true;
  } else {                                  // vT: 2 bz x 16 m x 16 n
    const int r = bid - 768;
    const int xcd = r & 7, idx = r >> 3;
    const int mt = (xcd << 1) + (idx & 1);
    const int rest = idx >> 1;
    const int nt = rest & 15, bz = rest >> 4;
    A = wvuT; BT = kvb + (long)bz * 2048 * 256; C = vTb + (long)bz * 2048 * 2048;
    N = 2048;
    m0 = mt << 7; n0 = nt << 7;
    is_k = false;
  }
  __shared__ alignas(16) u16 lA[128 * 64];
  __shared__ alignas(16) u16 lB[128 * 64];
  const int tid = threadIdx.x;
  const int w = tid >> 6, l = tid & 63;
  const int wr = w >> 1, wc = w & 1;
  const int lrow = l & 15, lg = l >> 4;
  const int srow = l >> 3, scol = (l & 7) << 3;
  f32x4 acc[4][4] = {};
  for (int kt = 0; kt < K; kt += 64) {
    __syncthreads();
#pragma unroll
    for (int i = 0; i < 4; i++) {
      const int chunk = (w << 2) + i;
      const int row = (chunk << 3) + srow;
      GLD_LDS16(A + (long)(m0 + row) * K + kt + scol, &lA[chunk << 9]);
      GLD_LDS16(BT + (long)(n0 + row) * K + kt + scol, &lB[chunk << 9]);
    }
    __syncthreads();
#pragma unroll
    for (int kk = 0; kk < 2; kk++) {
      bf16x8 af[4], bb[4];
#pragma unroll
      for (int i = 0; i < 4; i++) {
        af[i] = *(const bf16x8*)&lA[((wr << 6) + (i << 4) + lrow) * 64 + (kk << 5) + (lg << 3)];
        bb[i] = *(const bf16x8*)&lB[((wc << 6) + (i << 4) + lrow) * 64 + (kk << 5) + (lg << 3)];
      }
#pragma unroll
      for (int mi = 0; mi < 4; mi++)
#pragma unroll
        for (int ni = 0; ni < 4; ni++)
          acc[mi][ni] = MFMA16(af[mi], bb[ni], acc[mi][ni]);
    }
  }
  const int cbase_wave = n0 + (wc << 6);
  const bool ropewin = is_k && (cbase_wave % 192 == 128);
  const int sp = sp_ptr[0];
  epilogue_rope_store(C, N, acc, m0, wr, wc, cbase_wave, lrow, lg, ropewin, freqs, sp);
}

// ---------------------------- out GEMM: out = aob @ woT^T (f32 out), swizzled
__global__ __launch_bounds__(256, 2)
void gemm_out_kernel(const u16* __restrict__ A, const u16* __restrict__ BT,
                     float* __restrict__ C) {
  constexpr int K = 2048, N = 2048;
  const int bid = blockIdx.x;               // 512 = 32 m x 16 n
  const int xcd = bid & 7, idx = bid >> 3;
  const int m0 = ((xcd << 2) + (idx & 3)) << 7;
  const int n0 = (idx >> 2) << 7;
  __shared__ alignas(16) u16 lA[128 * 64];
  __shared__ alignas(16) u16 lB[128 * 64];
  const int tid = threadIdx.x;
  const int w = tid >> 6, l = tid & 63;
  const int wr = w >> 1, wc = w & 1;
  const int lrow = l & 15, lg = l >> 4;
  const int srow = l >> 3, scol = (l & 7) << 3;
  f32x4 acc[4][4] = {};
  for (int kt = 0; kt < K; kt += 64) {
    __syncthreads();
#pragma unroll
    for (int i = 0; i < 4; i++) {
      const int chunk = (w << 2) + i;
      const int row = (chunk << 3) + srow;
      GLD_LDS16(A + (long)(m0 + row) * K + kt + scol, &lA[chunk << 9]);
      GLD_LDS16(BT + (long)(n0 + row) * K + kt + scol, &lB[chunk << 9]);
    }
    __syncthreads();
#pragma unroll
    for (int kk = 0; kk < 2; kk++) {
      bf16x8 af[4], bb[4];
#pragma unroll
      for (int i = 0; i < 4; i++) {
        af[i] = *(const bf16x8*)&lA[((wr << 6) + (i << 4) + lrow) * 64 + (kk << 5) + (lg << 3)];
        bb[i] = *(const bf16x8*)&lB[((wc << 6) + (i << 4) + lrow) * 64 + (kk << 5) + (lg << 3)];
      }
#pragma unroll
      for (int mi = 0; mi < 4; mi++)
#pragma unroll
        for (int ni = 0; ni < 4; ni++)
          acc[mi][ni] = MFMA16(af[mi], bb[ni], acc[mi][ni]);
    }
  }
#pragma unroll
  for (int mi = 0; mi < 4; mi++) {
    const int r0 = m0 + (wr << 6) + (mi << 4) + (lg << 2);
#pragma unroll
    for (int ni = 0; ni < 4; ni++) {
      const int c0 = n0 + (wc << 6) + (ni << 4) + lrow;
#pragma unroll
      for (int r = 0; r < 4; r++)
        C[(long)(r0 + r) * N + c0] = acc[mi][ni][r];
    }
  }
}

// --------------------------------------------------- flash attention (split-KV)
// Round-16 proven math+staging (DMA-swizzled K/V, setprio, fixed-max softmax)
// + split-KV (partials combine by pure ADD) + SHARED per-wave P buffer:
// Pl 17.4->8.7KB => LDS 48.5KB => 3 blocks/CU (768 slots) so the 1024-block
// split grid runs in ~1.33 rounds (round-14's wash was 2.0 rounds at 512 slots).

__device__ __forceinline__ const u16* kaddr(const u16* Kl, int tb, int lrow, int jr_sw) {
  return &Kl[((tb << 4) + lrow) * 192 + (jr_sw << 3)];
}

__device__ __forceinline__ void attn_tile_step(
    const bf16x8* __restrict__ qf, f32x4* __restrict__ o, float* __restrict__ l_part,
    const int qrb, const int t0,
    const u16* __restrict__ Kl, const u16* __restrict__ Vl,
    u16* __restrict__ pw, const int lrow, const int lg) {
  constexpr float SCALE = 0.07216878364870323f;  // 1/sqrt(192)
  const int ks = lrow & 7;
  f32x4 s[4];
  __builtin_amdgcn_s_setprio(1);
#pragma unroll
  for (int tb = 0; tb < 4; tb++) {
    f32x4 a = {};
#pragma unroll
    for (int kb = 0; kb < 6; kb++) {
      const int jr = (kb << 2) + lg;
      const int jr_sw = (jr & 24) | ((jr & 7) ^ ks);
      bf16x8 kf = *(const bf16x8*)kaddr(Kl, tb, lrow, jr_sw);
      a = MFMA16(qf[kb], kf, a);
    }
    s[tb] = a;
  }
  __builtin_amdgcn_s_setprio(0);
#pragma unroll
  for (int tb = 0; tb < 4; tb++) {
    const int tt = t0 + (tb << 4) + lrow;
#pragma unroll
    for (int r = 0; r < 4; r++) {
      const int qrow = qrb + (lg << 2) + r;
      float p = __expf(s[tb][r] * SCALE);
      p = (tt <= qrow) ? p : 0.f;
      s[tb][r] = p;
      l_part[r] += p;
    }
  }
#pragma unroll
  for (int tb = 0; tb < 4; tb++)
#pragma unroll
    for (int r = 0; r < 4; r++)
      pw[((lg << 2) + r) * 68 + (tb << 4) + lrow] = f2bf(s[tb][r]);
  bf16x8 pf0 = *(const bf16x8*)&pw[lrow * 68 + (lg << 3)];
  bf16x8 pf1 = *(const bf16x8*)&pw[lrow * 68 + 32 + (lg << 3)];
  const int vc0 = (lg ^ ks) << 3, vc1 = ((4 + lg) ^ ks) << 3;
  __builtin_amdgcn_s_setprio(1);
#pragma unroll
  for (int db = 0; db < 8; db++) {
    const int vrow = ((db << 4) + lrow) << 6;  // *64
    bf16x8 v0 = *(const bf16x8*)&Vl[vrow + vc0];
    bf16x8 v1 = *(const bf16x8*)&Vl[vrow + vc1];
    o[db] = MFMA16(pf0, v0, o[db]);
    o[db] = MFMA16(pf1, v1, o[db]);
  }
  __builtin_amdgcn_s_setprio(0);
}

// Fused A+B step with SHARED P buffer: store P_A -> read pfA -> store P_B
// (same addresses; compiler must preserve order: provable aliasing) -> read pfB.
__device__ __forceinline__ void attn_tile_step2(
    const bf16x8* __restrict__ qfA, const bf16x8* __restrict__ qfB,
    f32x4* __restrict__ oA, f32x4* __restrict__ oB,
    float* __restrict__ lpA, float* __restrict__ lpB,
    const int qrbA, const int qrbB, const int t0,
    const u16* __restrict__ Kl, const u16* __restrict__ Vl,
    u16* __restrict__ pw, const int lrow, const int lg) {
  constexpr float SCALE = 0.07216878364870323f;  // 1/sqrt(192)
  const int ks = lrow & 7;
  f32x4 sA[4], sB[4];
  __builtin_amdgcn_s_setprio(1);
#pragma unroll
  for (int tb = 0; tb < 4; tb++) {
    f32x4 a = {}, bq = {};
#pragma unroll
    for (int kb = 0; kb < 6; kb++) {
      const int jr = (kb << 2) + lg;
      const int jr_sw = (jr & 24) | ((jr & 7) ^ ks);
      bf16x8 kf = *(const bf16x8*)kaddr(Kl, tb, lrow, jr_sw);
      a = MFMA16(qfA[kb], kf, a);
      bq = MFMA16(qfB[kb], kf, bq);
    }
    sA[tb] = a;
    sB[tb] = bq;
  }
  __builtin_amdgcn_s_setprio(0);
#pragma unroll
  for (int tb = 0; tb < 4; tb++) {
    const int tt = t0 + (tb << 4) + lrow;
#pragma unroll
    for (int r = 0; r < 4; r++) {
      const int qrowA = qrbA + (lg << 2) + r;
      float pA = __expf(sA[tb][r] * SCALE);
      pA = (tt <= qrowA) ? pA : 0.f;
      sA[tb][r] = pA;
      lpA[r] += pA;
      const int qrowB = qrbB + (lg << 2) + r;
      float pB = __expf(sB[tb][r] * SCALE);
      pB = (tt <= qrowB) ? pB : 0.f;
      sB[tb][r] = pB;
      lpB[r] += pB;
    }
  }
#pragma unroll
  for (int tb = 0; tb < 4; tb++)
#pragma unroll
    for (int r = 0; r < 4; r++)
      pw[((lg << 2) + r) * 68 + (tb << 4) + lrow] = f2bf(sA[tb][r]);
  bf16x8 pfA0 = *(const bf16x8*)&pw[lrow * 68 + (lg << 3)];
  bf16x8 pfA1 = *(const bf16x8*)&pw[lrow * 68 + 32 + (lg << 3)];
#pragma unroll
  for (int tb = 0; tb < 4; tb++)
#pragma unroll
    for (int r = 0; r < 4; r++)
      pw[((lg << 2) + r) * 68 + (tb << 4) + lrow] = f2bf(sB[tb][r]);
  bf16x8 pfB0 = *(const bf16x8*)&pw[lrow * 68 + (lg << 3)];
  bf16x8 pfB1 = *(const bf16x8*)&pw[lrow * 68 + 32 + (lg << 3)];
  const int vc0 = (lg ^ ks) << 3, vc1 = ((4 + lg) ^ ks) << 3;
  __builtin_amdgcn_s_setprio(1);
#pragma unroll
  for (int db = 0; db < 8; db++) {
    const int vrow = ((db << 4) + lrow) << 6;  // *64
    bf16x8 v0 = *(const bf16x8*)&Vl[vrow + vc0];
    bf16x8 v1 = *(const bf16x8*)&Vl[vrow + vc1];
    oA[db] = MFMA16(pfA0, v0, oA[db]);
    oB[db] = MFMA16(pfB0, v0, oB[db]);
    oA[db] = MFMA16(pfA1, v1, oA[db]);
    oB[db] = MFMA16(pfB1, v1, oB[db]);
  }
  __builtin_amdgcn_s_setprio(0);
}

// write UN-NORMALIZED partial o (bf16) + per-row partial l (f32, stride 16)
__device__ __forceinline__ void attn_write_part(
    u16* __restrict__ op, float* __restrict__ lp,
    const f32x4* __restrict__ o, const float* __restrict__ l_part,
    const int lrow, const int lg) {
#pragma unroll
  for (int r = 0; r < 4; r++) {
    float l = l_part[r];
#pragma unroll
    for (int d = 1; d < 16; d <<= 1) l += __shfl_xor(l, d);
    if (lrow == 0) lp[(long)((lg << 2) + r) * 16] = l;
#pragma unroll
    for (int db = 0; db < 8; db++)
      op[(long)((lg << 2) + r) * 2048 + (db << 4) + lrow] = f2bf(o[db][r]);
  }
}

// Split-KV triangle-paired causal flash attention. 1024 blocks = (s,pair,bh),
// XCD swizzle (bh%8 == bid%8). LDS 48.5KB -> 3 blocks/CU.
__global__ __launch_bounds__(256, 2)
void attn_kernel(const u16* __restrict__ q, const u16* __restrict__ k,
                 const u16* __restrict__ vT,
                 u16* __restrict__ o0p, u16* __restrict__ o1p,
                 float* __restrict__ l0p, float* __restrict__ l1p) {
  const int bid = blockIdx.x;
  const int xcd = bid & 7;
  const int rest = bid >> 3;                 // 0..127
  const int pair = rest & 15;
  const int s = (rest >> 4) & 1;
  const int bh = ((rest >> 5) << 3) | xcd;   // bh % 8 == XCD
  const int b = bh >> 4, h = bh & 15;
  const int tid = threadIdx.x, w = tid >> 6, l = tid & 63;
  const int lrow = l & 15, lg = l >> 4;
  const int qtA = pair, qtB = 31 - pair;
  const int qrbA = (qtA << 6) + (w << 4);
  const int qrbB = (qtB << 6) + (w << 4);
  const int EA = qtA + 1, EB = qtB + 1;        // tile counts
  const int hA = (EA + 1) >> 1, hB = (EB + 1) >> 1;
  __shared__ alignas(16) u16 Kl[64 * 192];     // linear [t][192]  (24.6KB)
  __shared__ alignas(16) u16 Vl[128 * 64];     // linear [d][64]   (16.4KB)
  __shared__ alignas(16) u16 Pl[4][16 * 68];   // per-wave SHARED P (8.7KB)

  bf16x8 qfA[6], qfB[6];
  {
    const u16* qbA = q + ((long)b * 2048 + qrbA + lrow) * 3072 + h * 192;
    const u16* qbB = q + ((long)b * 2048 + qrbB + lrow) * 3072 + h * 192;
#pragma unroll
    for (int kb = 0; kb < 6; kb++) {
      qfA[kb] = *(const bf16x8*)&qbA[(kb << 5) + (lg << 3)];
      qfB[kb] = *(const bf16x8*)&qbB[(kb << 5) + (lg << 3)];
    }
  }
  f32x4 oA[8] = {}, oB[8] = {};
  float lA[4] = {}, lB[4] = {};

  const u16* kbh = k + (long)b * 2048 * 3072 + h * 192;
  const u16* vbh = vT + ((long)b * 2048 + h * 128) * 2048;

  // swizzled DMA staging coordinates (round-16 proven)
  int krow_[6], kcol_[6], vrow_[4], vcol_[4];
#pragma unroll
  for (int i = 0; i < 6; i++) {
    const int c = (i << 8) + tid;
    krow_[i] = c / 24;
    const int j = c % 24;
    kcol_[i] = ((j & 24) | ((j & 7) ^ (krow_[i] & 7))) << 3;
  }
#pragma unroll
  for (int i = 0; i < 4; i++) {
    const int c = (i << 8) + tid;
    vrow_[i] = c >> 3;
    vcol_[i] = ((c & 7) ^ (vrow_[i] & 7)) << 3;
  }
  const int wbase = (tid & ~63) << 3;  // wave's chunk base * 8 u16

  auto stage = [&](int t0) {
    __syncthreads();
#pragma unroll
    for (int i = 0; i < 6; i++)
      GLD_LDS16(kbh + (long)(t0 + krow_[i]) * 3072 + kcol_[i], &Kl[(i << 11) + wbase]);
#pragma unroll
    for (int i = 0; i < 4; i++)
      GLD_LDS16(vbh + (long)vrow_[i] * 2048 + t0 + vcol_[i], &Vl[(i << 11) + wbase]);
    __syncthreads();
  };

  if (s == 0) {
    // front halves: A tiles [0,hA), B tiles [0,hB); hA <= hB
    for (int T = 0; T < hB; T++) {
      const int t0 = T << 6;
      stage(t0);
      if (T < hA)
        attn_tile_step2(qfA, qfB, oA, oB, lA, lB, qrbA, qrbB, t0, Kl, Vl,
                        &Pl[w][0], lrow, lg);
      else
        attn_tile_step(qfB, oB, lB, qrbB, t0, Kl, Vl, &Pl[w][0], lrow, lg);
    }
  } else {
    // back halves: A tiles [hA,EA), B tiles [hB,EB)
    for (int T = hA; T < EA; T++) {
      const int t0 = T << 6;
      stage(t0);
      attn_tile_step(qfA, oA, lA, qrbA, t0, Kl, Vl, &Pl[w][0], lrow, lg);
    }
    for (int T = hB; T < EB; T++) {
      const int t0 = T << 6;
      stage(t0);
      attn_tile_step(qfB, oB, lB, qrbB, t0, Kl, Vl, &Pl[w][0], lrow, lg);
    }
  }
  u16* op = s ? o1p : o0p;
  float* lp = s ? l1p : l0p;
  attn_write_part(op + ((long)b * 2048 + qrbA) * 2048 + (h << 7),
                  lp + ((long)b * 2048 + qrbA) * 16 + h, oA, lA, lrow, lg);
  attn_write_part(op + ((long)b * 2048 + qrbB) * 2048 + (h << 7),
                  lp + ((long)b * 2048 + qrbB) * 16 + h, oB, lB, lrow, lg);
}

// --------------------------- combine partials: aob = (o0+o1)/(l0+l1) -> bf16
__global__ void attn_norm_kernel(const u16* __restrict__ o0, const u16* __restrict__ o1,
                                 const float* __restrict__ l0, const float* __restrict__ l1,
                                 u16* __restrict__ aob) {
  const long i8 = ((long)blockIdx.x * 256 + threadIdx.x) << 3;  // 8 bf16 per thread
  const int row = (int)(i8 >> 11);
  const int h = ((int)i8 & 2047) >> 7;
  const float linv = 1.f / (l0[row * 16 + h] + l1[row * 16 + h]);
  union { u16 s[8]; uint4 u; } pa, pb, po;
  pa.u = *(const uint4*)(o0 + i8);
  pb.u = *(const uint4*)(o1 + i8);
#pragma unroll
  for (int j = 0; j < 8; j++)
    po.s[j] = f2bf((bf2f(pa.s[j]) + bf2f(pb.s[j])) * linv);
  *(uint4*)(aob + i8) = po.u;
}

// ----------------------------------------------------------------- launch
extern "C" void kernel_launch(void* const* d_in, const int* in_sizes, int n_in,
                              void* d_out, int out_size, void* d_ws, size_t ws_size,
                              hipStream_t stream) {
  const float* x = (const float*)d_in[0];
  const float* fcis = (const float*)d_in[1];
  const float* w_q = (const float*)d_in[2];
  const float* w_kvd = (const float*)d_in[3];
  const float* w_ku = (const float*)d_in[4];
  const float* w_vu = (const float*)d_in[5];
  const float* w_o = (const float*)d_in[6];
  const int* start_pos = (const int*)d_in[7];
  float* out = (float*)d_out;

  char* p = (char*)d_ws;
  auto alloc = [&](long bytes) -> char* {
    char* r = p;
    p += (bytes + 255) & ~255ll;
    return r;
  };
  // long-lived buffers
  u16* xb = (u16*)alloc(4096ll * 2048 * 2);    // x bf16; later aliased as vT
  u16* qb = (u16*)alloc(4096ll * 3072 * 2);    // q (rope fused)
  u16* kb = (u16*)alloc(4096ll * 3072 * 2);    // k (rope fused)
  u16* aob = (u16*)alloc(4096ll * 2048 * 2);   // attention out (combined)
  u16* woT = (u16*)alloc(2048ll * 2048 * 2);   // w_o^T (used by last GEMM)
  // dead-after-GEMM pool (overlaid by attention partials)
  char* pool = p;
  u16* wqT = (u16*)alloc(3072ll * 2048 * 2);   // dead after q_kvd
  u16* wkdT = (u16*)alloc(256ll * 2048 * 2);   // dead after q_kvd
  u16* wkuT = (u16*)alloc(3072ll * 256 * 2);   // dead after kup_vt
  u16* wvuT = (u16*)alloc(2048ll * 256 * 2);   // dead after kup_vt
  u16* kvb = (u16*)alloc(4096ll * 256 * 2);    // dead after kup_vt
  // attention partial buffers overlay the pool (lifetimes disjoint)
  u16* o0p = (u16*)pool;                                  // 16 MB
  u16* o1p = (u16*)(pool + 16777216);                     // 16 MB
  float* l0p = (float*)(pool + 2 * 16777216);             // 256 KB
  float* l1p = (float*)(pool + 2 * 16777216 + 262144);    // 256 KB
  {
    char* endp = pool + 2 * 16777216 + 2 * 262144;
    if (endp > p) p = endp;
  }
  u16* vTb = xb;  // alias: x-bf16 dead before the vT GEMM runs (stream order)

  // merged conv + all 5 weight transposes: 14080 blocks of (32,8)
  prep_kernel<<<14080, dim3(32, 8), 0, stream>>>(x, xb, w_q, wqT, w_kvd, wkdT,
                                                 w_ku, wkuT, w_vu, wvuT, w_o, woT);
  // fused q = x@w_q (+RoPE) and kv = x@w_kv_down; XCD m-band swizzled
  gemm_q_kvd_kernel<<<832, 256, 0, stream>>>(xb, wqT, wkdT, qb, kvb, fcis, start_pos);
  // merged k = kv@w_k_up (+RoPE) + vT = w_v_up^T@kv^T; XCD m-band swizzled
  gemm_kup_vt_kernel<<<1280, 256, 0, stream>>>(kvb, wkuT, wvuT, kb, vTb, fcis, start_pos);
  // split-KV attention: 1024 blocks (2 splits x 16 pairs x 32 bh), 3 blocks/CU
  attn_kernel<<<1024, 256, 0, stream>>>(qb, kb, vTb, o0p, o1p, l0p, l1p);
  // combine + normalize partials -> aob (bf16)
  attn_norm_kernel<<<4096, 256, 0, stream>>>(o0p, o1p, l0p, l1p, aob);
  // out = attn_out @ w_o -> f32; XCD m-band swizzled
  gemm_out_kernel<<<512, 256, 0, stream>>>(aob, woT, out);
}

// Round 18
// 247.030 us; speedup vs baseline: 1.0978x; 1.0978x over previous
//
#include <hip/hip_runtime.h>
#include <stdint.h>

typedef unsigned short u16;
typedef float f32x4 __attribute__((ext_vector_type(4)));
typedef __bf16 bf16x8 __attribute__((ext_vector_type(8)));

static __device__ __forceinline__ u16 f2bf(float f) {
  union { float f; unsigned u; } v; v.f = f;
  unsigned r = v.u + 0x7fffu + ((v.u >> 16) & 1u);   // RNE
  return (u16)(r >> 16);
}
static __device__ __forceinline__ float bf2f(u16 h) {
  union { unsigned u; float f; } v; v.u = ((unsigned)h) << 16;
  return v.f;
}

#define GLD_LDS16(gp, lp) __builtin_amdgcn_global_load_lds( \
    (__attribute__((address_space(1))) void*)(gp),          \
    (__attribute__((address_space(3))) void*)(lp), 16, 0, 0)

#define MFMA16(a, b, c) __builtin_amdgcn_mfma_f32_16x16x32_bf16((a), (b), (c), 0, 0, 0)

// ---------------------------------------------- merged prep: conv + 5 transposes
__global__ void prep_kernel(const float* __restrict__ x, u16* __restrict__ xb,
                            const float* __restrict__ w_q, u16* __restrict__ wqT,
                            const float* __restrict__ w_kvd, u16* __restrict__ wkdT,
                            const float* __restrict__ w_ku, u16* __restrict__ wkuT,
                            const float* __restrict__ w_vu, u16* __restrict__ wvuT,
                            const float* __restrict__ w_o, u16* __restrict__ woT) {
  __shared__ float tile[32][33];
  const int bid = blockIdx.x;
  const int tx = threadIdx.x, ty = threadIdx.y;
  if (bid < 2048) {
    const int tid = ty * 32 + tx;
    const long n = 4096ll * 2048;
    const long stride = 2048ll * 256 * 4;
    for (long i = ((long)bid * 256 + tid) * 4; i < n; i += stride) {
      float4 v = *(const float4*)(x + i);
      union { u16 s[4]; uint2 u; } pk;
      pk.s[0] = f2bf(v.x); pk.s[1] = f2bf(v.y); pk.s[2] = f2bf(v.z); pk.s[3] = f2bf(v.w);
      *(uint2*)(xb + i) = pk.u;
    }
    return;
  }
  const float* W; u16* WT; int K, N, bx, by;
  int r = bid - 2048;
  if (r < 6144)        { W = w_q;   WT = wqT;  K = 2048; N = 3072; bx = r % 96; by = r / 96; }
  else if ((r -= 6144) < 512) { W = w_kvd; WT = wkdT; K = 2048; N = 256;  bx = r % 8;  by = r / 8; }
  else if ((r -= 512) < 768)  { W = w_ku;  WT = wkuT; K = 256;  N = 3072; bx = r % 96; by = r / 96; }
  else if ((r -= 768) < 512)  { W = w_vu;  WT = wvuT; K = 256;  N = 2048; bx = r % 64; by = r / 64; }
  else                 { r -= 512; W = w_o; WT = woT; K = 2048; N = 2048; bx = r % 64; by = r / 64; }
  const int n0 = bx * 32, k0 = by * 32;
#pragma unroll
  for (int i = 0; i < 32; i += 8) tile[ty + i][tx] = W[(long)(k0 + ty + i) * N + n0 + tx];
  __syncthreads();
#pragma unroll
  for (int i = 0; i < 32; i += 8)
    WT[(long)(n0 + ty + i) * K + k0 + tx] = f2bf(tile[tx][ty + i]);
}

// ------------------- fused-rope epilogue helper (q/k layout [row][h*192+d])
__device__ __forceinline__ void epilogue_rope_store(
    u16* __restrict__ C, const int N, const f32x4 (*acc)[4],
    const int m0, const int wr, const int wc, const int cbase_wave,
    const int lrow, const int lg, const bool ropewin,
    const float* __restrict__ freqs, const int sp) {
#pragma unroll
  for (int mi = 0; mi < 4; mi++) {
    const int r0 = m0 + (wr << 6) + (mi << 4) + (lg << 2);
#pragma unroll
    for (int r = 0; r < 4; r++) {
      float v0 = acc[mi][0][r], v1 = acc[mi][1][r];
      float v2 = acc[mi][2][r], v3 = acc[mi][3][r];
      if (ropewin) {
        const int t = (r0 + r) & 2047;
        const float2 cs0 = *(const float2*)&freqs[((long)(sp + t) * 32 + lrow) * 2];
        const float2 cs1 = *(const float2*)&freqs[((long)(sp + t) * 32 + 16 + lrow) * 2];
        const float n0v = v0 * cs0.x - v2 * cs0.y;
        const float n1v = v1 * cs1.x - v3 * cs1.y;
        const float n2v = v2 * cs0.x + v0 * cs0.y;
        const float n3v = v3 * cs1.x + v1 * cs1.y;
        v0 = n0v; v1 = n1v; v2 = n2v; v3 = n3v;
      }
      const long ro = (long)(r0 + r) * N + cbase_wave + lrow;
      C[ro] = f2bf(v0);
      C[ro + 16] = f2bf(v1);
      C[ro + 32] = f2bf(v2);
      C[ro + 48] = f2bf(v3);
    }
  }
}

// --------------------------------------- fused q + kv_down GEMM (shared A=xb)
// launch_bounds (256,4): VGPR 76 fits 128-cap; LDS 32KB -> 4 blocks/CU resident
// (was effectively ~2 at (256,2)) for latency hiding on this 2-phase loop.
__global__ __launch_bounds__(256, 4)
void gemm_q_kvd_kernel(const u16* __restrict__ A, const u16* __restrict__ wqT,
                       const u16* __restrict__ wkdT, u16* __restrict__ qb,
                       u16* __restrict__ kvb,
                       const float* __restrict__ freqs, const int* __restrict__ sp_ptr) {
  constexpr int K = 2048;
  const int bid = blockIdx.x;
  const int xcd = bid & 7;
  const int idx = bid >> 3;                 // 0..103
  const int m0 = ((xcd << 2) + (idx & 3)) << 7;
  const int n0raw = (idx >> 2) << 7;        // n-tile 0..25
  const bool is_kv = n0raw >= 3072;
  const u16* BT = is_kv ? (wkdT + (long)(n0raw - 3072) * K) : (wqT + (long)n0raw * K);
  u16* C = is_kv ? kvb : qb;
  const int N = is_kv ? 256 : 3072;
  const int c_base = is_kv ? (n0raw - 3072) : n0raw;
  __shared__ alignas(16) u16 lA[128 * 64];
  __shared__ alignas(16) u16 lB[128 * 64];
  const int tid = threadIdx.x;
  const int w = tid >> 6, l = tid & 63;
  const int wr = w >> 1, wc = w & 1;
  const int lrow = l & 15, lg = l >> 4;
  const int srow = l >> 3, scol = (l & 7) << 3;
  f32x4 acc[4][4] = {};
  for (int kt = 0; kt < K; kt += 64) {
    __syncthreads();
#pragma unroll
    for (int i = 0; i < 4; i++) {
      const int chunk = (w << 2) + i;
      const int row = (chunk << 3) + srow;
      GLD_LDS16(A + (long)(m0 + row) * K + kt + scol, &lA[chunk << 9]);
      GLD_LDS16(BT + (long)row * K + kt + scol, &lB[chunk << 9]);
    }
    __syncthreads();
#pragma unroll
    for (int kk = 0; kk < 2; kk++) {
      bf16x8 af[4], bb[4];
#pragma unroll
      for (int i = 0; i < 4; i++) {
        af[i] = *(const bf16x8*)&lA[((wr << 6) + (i << 4) + lrow) * 64 + (kk << 5) + (lg << 3)];
        bb[i] = *(const bf16x8*)&lB[((wc << 6) + (i << 4) + lrow) * 64 + (kk << 5) + (lg << 3)];
      }
#pragma unroll
      for (int mi = 0; mi < 4; mi++)
#pragma unroll
        for (int ni = 0; ni < 4; ni++)
          acc[mi][ni] = MFMA16(af[mi], bb[ni], acc[mi][ni]);
    }
  }
  const int cbase_wave = c_base + (wc << 6);
  const bool ropewin = (!is_kv) && (cbase_wave % 192 == 128);
  const int sp = sp_ptr[0];
  epilogue_rope_store(C, N, acc, m0, wr, wc, cbase_wave, lrow, lg, ropewin, freqs, sp);
}

// ---------------------------- merged k_up + vT GEMM (both K=256, read kvb)
__global__ __launch_bounds__(256, 4)
void gemm_kup_vt_kernel(const u16* __restrict__ kvb, const u16* __restrict__ wkuT,
                        const u16* __restrict__ wvuT, u16* __restrict__ kb,
                        u16* __restrict__ vTb,
                        const float* __restrict__ freqs, const int* __restrict__ sp_ptr) {
  constexpr int K = 256;
  const int bid = blockIdx.x;
  const u16 *A, *BT;
  u16* C;
  int N, m0, n0;
  bool is_k;
  if (bid < 768) {                          // k-up: 32 m-tiles x 24 n-tiles
    const int xcd = bid & 7, idx = bid >> 3;
    A = kvb; BT = wkuT; C = kb; N = 3072;
    m0 = ((xcd << 2) + (idx & 3)) << 7;
    n0 = (idx >> 2) << 7;
    is_k = true;
  } else {                                  // vT: 2 bz x 16 m x 16 n
    const int r = bid - 768;
    const int xcd = r & 7, idx = r >> 3;
    const int mt = (xcd << 1) + (idx & 1);
    const int rest = idx >> 1;
    const int nt = rest & 15, bz = rest >> 4;
    A = wvuT; BT = kvb + (long)bz * 2048 * 256; C = vTb + (long)bz * 2048 * 2048;
    N = 2048;
    m0 = mt << 7; n0 = nt << 7;
    is_k = false;
  }
  __shared__ alignas(16) u16 lA[128 * 64];
  __shared__ alignas(16) u16 lB[128 * 64];
  const int tid = threadIdx.x;
  const int w = tid >> 6, l = tid & 63;
  const int wr = w >> 1, wc = w & 1;
  const int lrow = l & 15, lg = l >> 4;
  const int srow = l >> 3, scol = (l & 7) << 3;
  f32x4 acc[4][4] = {};
  for (int kt = 0; kt < K; kt += 64) {
    __syncthreads();
#pragma unroll
    for (int i = 0; i < 4; i++) {
      const int chunk = (w << 2) + i;
      const int row = (chunk << 3) + srow;
      GLD_LDS16(A + (long)(m0 + row) * K + kt + scol, &lA[chunk << 9]);
      GLD_LDS16(BT + (long)(n0 + row) * K + kt + scol, &lB[chunk << 9]);
    }
    __syncthreads();
#pragma unroll
    for (int kk = 0; kk < 2; kk++) {
      bf16x8 af[4], bb[4];
#pragma unroll
      for (int i = 0; i < 4; i++) {
        af[i] = *(const bf16x8*)&lA[((wr << 6) + (i << 4) + lrow) * 64 + (kk << 5) + (lg << 3)];
        bb[i] = *(const bf16x8*)&lB[((wc << 6) + (i << 4) + lrow) * 64 + (kk << 5) + (lg << 3)];
      }
#pragma unroll
      for (int mi = 0; mi < 4; mi++)
#pragma unroll
        for (int ni = 0; ni < 4; ni++)
          acc[mi][ni] = MFMA16(af[mi], bb[ni], acc[mi][ni]);
    }
  }
  const int cbase_wave = n0 + (wc << 6);
  const bool ropewin = is_k && (cbase_wave % 192 == 128);
  const int sp = sp_ptr[0];
  epilogue_rope_store(C, N, acc, m0, wr, wc, cbase_wave, lrow, lg, ropewin, freqs, sp);
}

// ---------------------------- out GEMM: out = aob @ woT^T (f32 out), swizzled
__global__ __launch_bounds__(256, 4)
void gemm_out_kernel(const u16* __restrict__ A, const u16* __restrict__ BT,
                     float* __restrict__ C) {
  constexpr int K = 2048, N = 2048;
  const int bid = blockIdx.x;               // 512 = 32 m x 16 n
  const int xcd = bid & 7, idx = bid >> 3;
  const int m0 = ((xcd << 2) + (idx & 3)) << 7;
  const int n0 = (idx >> 2) << 7;
  __shared__ alignas(16) u16 lA[128 * 64];
  __shared__ alignas(16) u16 lB[128 * 64];
  const int tid = threadIdx.x;
  const int w = tid >> 6, l = tid & 63;
  const int wr = w >> 1, wc = w & 1;
  const int lrow = l & 15, lg = l >> 4;
  const int srow = l >> 3, scol = (l & 7) << 3;
  f32x4 acc[4][4] = {};
  for (int kt = 0; kt < K; kt += 64) {
    __syncthreads();
#pragma unroll
    for (int i = 0; i < 4; i++) {
      const int chunk = (w << 2) + i;
      const int row = (chunk << 3) + srow;
      GLD_LDS16(A + (long)(m0 + row) * K + kt + scol, &lA[chunk << 9]);
      GLD_LDS16(BT + (long)(n0 + row) * K + kt + scol, &lB[chunk << 9]);
    }
    __syncthreads();
#pragma unroll
    for (int kk = 0; kk < 2; kk++) {
      bf16x8 af[4], bb[4];
#pragma unroll
      for (int i = 0; i < 4; i++) {
        af[i] = *(const bf16x8*)&lA[((wr << 6) + (i << 4) + lrow) * 64 + (kk << 5) + (lg << 3)];
        bb[i] = *(const bf16x8*)&lB[((wc << 6) + (i << 4) + lrow) * 64 + (kk << 5) + (lg << 3)];
      }
#pragma unroll
      for (int mi = 0; mi < 4; mi++)
#pragma unroll
        for (int ni = 0; ni < 4; ni++)
          acc[mi][ni] = MFMA16(af[mi], bb[ni], acc[mi][ni]);
    }
  }
#pragma unroll
  for (int mi = 0; mi < 4; mi++) {
    const int r0 = m0 + (wr << 6) + (mi << 4) + (lg << 2);
#pragma unroll
    for (int ni = 0; ni < 4; ni++) {
      const int c0 = n0 + (wc << 6) + (ni << 4) + lrow;
#pragma unroll
      for (int r = 0; r < 4; r++)
        C[(long)(r0 + r) * N + c0] = acc[mi][ni][r];
    }
  }
}

// --------------------------------------------------- flash attention (paired)
// Round-16 proven kernel verbatim (best: 263.9us total): DMA-swizzled K/V
// staging, separate per-wave P buffers, setprio, fixed-max softmax.
// (Split-KV closed: two attempts both net-regressed on overhead.)

__device__ __forceinline__ const u16* kaddr(const u16* Kl, int tb, int lrow, int jr_sw) {
  return &Kl[((tb << 4) + lrow) * 192 + (jr_sw << 3)];
}

__device__ __forceinline__ void attn_tile_step(
    const bf16x8* __restrict__ qf, f32x4* __restrict__ o, float* __restrict__ l_part,
    const int qrb, const int t0,
    const u16* __restrict__ Kl, const u16* __restrict__ Vl,
    u16* __restrict__ pw, const int lrow, const int lg) {
  constexpr float SCALE = 0.07216878364870323f;  // 1/sqrt(192)
  const int ks = lrow & 7;
  f32x4 s[4];
  __builtin_amdgcn_s_setprio(1);
#pragma unroll
  for (int tb = 0; tb < 4; tb++) {
    f32x4 a = {};
#pragma unroll
    for (int kb = 0; kb < 6; kb++) {
      const int jr = (kb << 2) + lg;
      const int jr_sw = (jr & 24) | ((jr & 7) ^ ks);
      bf16x8 kf = *(const bf16x8*)kaddr(Kl, tb, lrow, jr_sw);
      a = MFMA16(qf[kb], kf, a);
    }
    s[tb] = a;
  }
  __builtin_amdgcn_s_setprio(0);
#pragma unroll
  for (int tb = 0; tb < 4; tb++) {
    const int tt = t0 + (tb << 4) + lrow;
#pragma unroll
    for (int r = 0; r < 4; r++) {
      const int qrow = qrb + (lg << 2) + r;
      float p = __expf(s[tb][r] * SCALE);
      p = (tt <= qrow) ? p : 0.f;
      s[tb][r] = p;
      l_part[r] += p;
    }
  }
#pragma unroll
  for (int tb = 0; tb < 4; tb++)
#pragma unroll
    for (int r = 0; r < 4; r++)
      pw[((lg << 2) + r) * 68 + (tb << 4) + lrow] = f2bf(s[tb][r]);
  bf16x8 pf0 = *(const bf16x8*)&pw[lrow * 68 + (lg << 3)];
  bf16x8 pf1 = *(const bf16x8*)&pw[lrow * 68 + 32 + (lg << 3)];
  const int vc0 = (lg ^ ks) << 3, vc1 = ((4 + lg) ^ ks) << 3;
  __builtin_amdgcn_s_setprio(1);
#pragma unroll
  for (int db = 0; db < 8; db++) {
    const int vrow = ((db << 4) + lrow) << 6;  // *64
    bf16x8 v0 = *(const bf16x8*)&Vl[vrow + vc0];
    bf16x8 v1 = *(const bf16x8*)&Vl[vrow + vc1];
    o[db] = MFMA16(pf0, v0, o[db]);
    o[db] = MFMA16(pf1, v1, o[db]);
  }
  __builtin_amdgcn_s_setprio(0);
}

__device__ __forceinline__ void attn_tile_step2(
    const bf16x8* __restrict__ qfA, const bf16x8* __restrict__ qfB,
    f32x4* __restrict__ oA, f32x4* __restrict__ oB,
    float* __restrict__ lpA, float* __restrict__ lpB,
    const int qrbA, const int qrbB, const int t0,
    const u16* __restrict__ Kl, const u16* __restrict__ Vl,
    u16* __restrict__ pwA, u16* __restrict__ pwB, const int lrow, const int lg) {
  constexpr float SCALE = 0.07216878364870323f;  // 1/sqrt(192)
  const int ks = lrow & 7;
  f32x4 sA[4], sB[4];
  __builtin_amdgcn_s_setprio(1);
#pragma unroll
  for (int tb = 0; tb < 4; tb++) {
    f32x4 a = {}, bq = {};
#pragma unroll
    for (int kb = 0; kb < 6; kb++) {
      const int jr = (kb << 2) + lg;
      const int jr_sw = (jr & 24) | ((jr & 7) ^ ks);
      bf16x8 kf = *(const bf16x8*)kaddr(Kl, tb, lrow, jr_sw);
      a = MFMA16(qfA[kb], kf, a);
      bq = MFMA16(qfB[kb], kf, bq);
    }
    sA[tb] = a;
    sB[tb] = bq;
  }
  __builtin_amdgcn_s_setprio(0);
#pragma unroll
  for (int tb = 0; tb < 4; tb++) {
    const int tt = t0 + (tb << 4) + lrow;
#pragma unroll
    for (int r = 0; r < 4; r++) {
      const int qrowA = qrbA + (lg << 2) + r;
      float pA = __expf(sA[tb][r] * SCALE);
      pA = (tt <= qrowA) ? pA : 0.f;
      sA[tb][r] = pA;
      lpA[r] += pA;
      const int qrowB = qrbB + (lg << 2) + r;
      float pB = __expf(sB[tb][r] * SCALE);
      pB = (tt <= qrowB) ? pB : 0.f;
      sB[tb][r] = pB;
      lpB[r] += pB;
    }
  }
#pragma unroll
  for (int tb = 0; tb < 4; tb++)
#pragma unroll
    for (int r = 0; r < 4; r++) {
      pwA[((lg << 2) + r) * 68 + (tb << 4) + lrow] = f2bf(sA[tb][r]);
      pwB[((lg << 2) + r) * 68 + (tb << 4) + lrow] = f2bf(sB[tb][r]);
    }
  bf16x8 pfA0 = *(const bf16x8*)&pwA[lrow * 68 + (lg << 3)];
  bf16x8 pfA1 = *(const bf16x8*)&pwA[lrow * 68 + 32 + (lg << 3)];
  bf16x8 pfB0 = *(const bf16x8*)&pwB[lrow * 68 + (lg << 3)];
  bf16x8 pfB1 = *(const bf16x8*)&pwB[lrow * 68 + 32 + (lg << 3)];
  const int vc0 = (lg ^ ks) << 3, vc1 = ((4 + lg) ^ ks) << 3;
  __builtin_amdgcn_s_setprio(1);
#pragma unroll
  for (int db = 0; db < 8; db++) {
    const int vrow = ((db << 4) + lrow) << 6;  // *64
    bf16x8 v0 = *(const bf16x8*)&Vl[vrow + vc0];
    bf16x8 v1 = *(const bf16x8*)&Vl[vrow + vc1];
    oA[db] = MFMA16(pfA0, v0, oA[db]);
    oB[db] = MFMA16(pfB0, v0, oB[db]);
    oA[db] = MFMA16(pfA1, v1, oA[db]);
    oB[db] = MFMA16(pfB1, v1, oB[db]);
  }
  __builtin_amdgcn_s_setprio(0);
}

__device__ __forceinline__ void attn_write(
    u16* __restrict__ ob, const f32x4* __restrict__ o, const float* __restrict__ l_part,
    const int lrow, const int lg) {
#pragma unroll
  for (int r = 0; r < 4; r++) {
    float l = l_part[r];
#pragma unroll
    for (int d = 1; d < 16; d <<= 1) l += __shfl_xor(l, d);
    const float inv = 1.f / l;
#pragma unroll
    for (int db = 0; db < 8; db++)
      ob[(long)((lg << 2) + r) * 2048 + (db << 4) + lrow] = f2bf(o[db][r] * inv);
  }
}

// Triangle-paired causal flash attention, XCD-swizzled (bh%8 == bid%8),
// 512 blocks x 256 threads. K/V staged via swizzled global_load_lds DMA.
__global__ __launch_bounds__(256, 2)
void attn_kernel(const u16* __restrict__ q, const u16* __restrict__ k,
                 const u16* __restrict__ vT, u16* __restrict__ out) {
  const int bid = blockIdx.x;
  const int xcd = bid & 7;
  const int rest = bid >> 3;
  const int pair = rest & 15;
  const int bh = ((rest >> 4) << 3) | xcd;   // bh % 8 == XCD
  const int b = bh >> 4, h = bh & 15;
  const int tid = threadIdx.x, w = tid >> 6, l = tid & 63;
  const int lrow = l & 15, lg = l >> 4;
  const int qtA = pair, qtB = 31 - pair;
  const int qrbA = (qtA << 6) + (w << 4);
  const int qrbB = (qtB << 6) + (w << 4);
  __shared__ alignas(16) u16 Kl[64 * 192];      // linear [t][192]  (24.6KB)
  __shared__ alignas(16) u16 Vl[128 * 64];      // linear [d][64]   (16.4KB)
  __shared__ alignas(16) u16 Pl[4][2][16 * 68]; // per-wave P x{A,B}(17.4KB)

  bf16x8 qfA[6], qfB[6];
  {
    const u16* qbA = q + ((long)b * 2048 + qrbA + lrow) * 3072 + h * 192;
    const u16* qbB = q + ((long)b * 2048 + qrbB + lrow) * 3072 + h * 192;
#pragma unroll
    for (int kb = 0; kb < 6; kb++) {
      qfA[kb] = *(const bf16x8*)&qbA[(kb << 5) + (lg << 3)];
      qfB[kb] = *(const bf16x8*)&qbB[(kb << 5) + (lg << 3)];
    }
  }
  f32x4 oA[8] = {}, oB[8] = {};
  float lA[4] = {}, lB[4] = {};

  const u16* kbh = k + (long)b * 2048 * 3072 + h * 192;
  const u16* vbh = vT + ((long)b * 2048 + h * 128) * 2048;
  const int tEndA = qtA << 6, tEndB = qtB << 6;

  int krow_[6], kcol_[6], vrow_[4], vcol_[4];
#pragma unroll
  for (int i = 0; i < 6; i++) {
    const int c = (i << 8) + tid;
    krow_[i] = c / 24;
    const int j = c % 24;
    kcol_[i] = ((j & 24) | ((j & 7) ^ (krow_[i] & 7))) << 3;
  }
#pragma unroll
  for (int i = 0; i < 4; i++) {
    const int c = (i << 8) + tid;
    vrow_[i] = c >> 3;
    vcol_[i] = ((c & 7) ^ (vrow_[i] & 7)) << 3;
  }
  const int wbase = (tid & ~63) << 3;  // wave's chunk base * 8 u16

  for (int t0 = 0; t0 <= tEndB; t0 += 64) {
    __syncthreads();
#pragma unroll
    for (int i = 0; i < 6; i++)
      GLD_LDS16(kbh + (long)(t0 + krow_[i]) * 3072 + kcol_[i], &Kl[(i << 11) + wbase]);
#pragma unroll
    for (int i = 0; i < 4; i++)
      GLD_LDS16(vbh + (long)vrow_[i] * 2048 + t0 + vcol_[i], &Vl[(i << 11) + wbase]);
    __syncthreads();
    if (t0 <= tEndA)
      attn_tile_step2(qfA, qfB, oA, oB, lA, lB, qrbA, qrbB, t0, Kl, Vl,
                      &Pl[w][0][0], &Pl[w][1][0], lrow, lg);
    else
      attn_tile_step(qfB, oB, lB, qrbB, t0, Kl, Vl, &Pl[w][1][0], lrow, lg);
  }
  attn_write(out + ((long)b * 2048 + qrbA) * 2048 + (h << 7), oA, lA, lrow, lg);
  attn_write(out + ((long)b * 2048 + qrbB) * 2048 + (h << 7), oB, lB, lrow, lg);
}

// ----------------------------------------------------------------- launch
extern "C" void kernel_launch(void* const* d_in, const int* in_sizes, int n_in,
                              void* d_out, int out_size, void* d_ws, size_t ws_size,
                              hipStream_t stream) {
  const float* x = (const float*)d_in[0];
  const float* fcis = (const float*)d_in[1];
  const float* w_q = (const float*)d_in[2];
  const float* w_kvd = (const float*)d_in[3];
  const float* w_ku = (const float*)d_in[4];
  const float* w_vu = (const float*)d_in[5];
  const float* w_o = (const float*)d_in[6];
  const int* start_pos = (const int*)d_in[7];
  float* out = (float*)d_out;

  char* p = (char*)d_ws;
  auto alloc = [&](long bytes) -> char* {
    char* r = p;
    p += (bytes + 255) & ~255ll;
    return r;
  };
  u16* xb = (u16*)alloc(4096ll * 2048 * 2);    // x bf16
  u16* wqT = (u16*)alloc(3072ll * 2048 * 2);   // w_q^T
  u16* wkdT = (u16*)alloc(256ll * 2048 * 2);   // w_kv_down^T
  u16* wkuT = (u16*)alloc(3072ll * 256 * 2);   // w_k_up^T
  u16* wvuT = (u16*)alloc(2048ll * 256 * 2);   // w_v_up^T
  u16* woT = (u16*)alloc(2048ll * 2048 * 2);   // w_o^T
  u16* qb = (u16*)alloc(4096ll * 3072 * 2);    // q (rope fused in epilogue)
  u16* kvb = (u16*)alloc(4096ll * 256 * 2);    // kv
  u16* kb = (u16*)alloc(4096ll * 3072 * 2);    // k (rope fused in epilogue)
  u16* aob = (u16*)alloc(4096ll * 2048 * 2);   // attention out
  u16* vTb = xb;  // alias: x-bf16 is dead before the vT GEMM runs (stream order)

  // merged conv + all 5 weight transposes: 14080 blocks of (32,8)
  prep_kernel<<<14080, dim3(32, 8), 0, stream>>>(x, xb, w_q, wqT, w_kvd, wkdT,
                                                 w_ku, wkuT, w_vu, wvuT, w_o, woT);
  // fused q = x@w_q (+RoPE) and kv = x@w_kv_down; XCD m-band swizzled
  gemm_q_kvd_kernel<<<832, 256, 0, stream>>>(xb, wqT, wkdT, qb, kvb, fcis, start_pos);
  // merged k = kv@w_k_up (+RoPE) + vT = w_v_up^T@kv^T; XCD m-band swizzled
  gemm_kup_vt_kernel<<<1280, 256, 0, stream>>>(kvb, wkuT, wvuT, kb, vTb, fcis, start_pos);
  // XCD-swizzled triangle-paired attention: 512 blocks x 256 threads
  attn_kernel<<<512, 256, 0, stream>>>(qb, kb, vTb, aob);
  // out = attn_out @ w_o -> f32; XCD m-band swizzled
  gemm_out_kernel<<<512, 256, 0, stream>>>(aob, woT, out);
}

// Round 19
// 243.998 us; speedup vs baseline: 1.1115x; 1.0124x over previous
//
#include <hip/hip_runtime.h>
#include <stdint.h>

typedef unsigned short u16;
typedef float f32x4 __attribute__((ext_vector_type(4)));
typedef __bf16 bf16x8 __attribute__((ext_vector_type(8)));

static __device__ __forceinline__ u16 f2bf(float f) {
  union { float f; unsigned u; } v; v.f = f;
  unsigned r = v.u + 0x7fffu + ((v.u >> 16) & 1u);   // RNE
  return (u16)(r >> 16);
}
static __device__ __forceinline__ float bf2f(u16 h) {
  union { unsigned u; float f; } v; v.u = ((unsigned)h) << 16;
  return v.f;
}
// native scalar cast (RNE) — compiler lowers to 1-2 VALU ops (m240)
static __device__ __forceinline__ u16 f2bf_n(float f) {
  __bf16 h = (__bf16)f;
  return *(u16*)&h;
}

#define GLD_LDS16(gp, lp) __builtin_amdgcn_global_load_lds( \
    (__attribute__((address_space(1))) void*)(gp),          \
    (__attribute__((address_space(3))) void*)(lp), 16, 0, 0)

#define MFMA16(a, b, c) __builtin_amdgcn_mfma_f32_16x16x32_bf16((a), (b), (c), 0, 0, 0)

// ---------------------------------------------- merged prep: conv + 5 transposes
__global__ void prep_kernel(const float* __restrict__ x, u16* __restrict__ xb,
                            const float* __restrict__ w_q, u16* __restrict__ wqT,
                            const float* __restrict__ w_kvd, u16* __restrict__ wkdT,
                            const float* __restrict__ w_ku, u16* __restrict__ wkuT,
                            const float* __restrict__ w_vu, u16* __restrict__ wvuT,
                            const float* __restrict__ w_o, u16* __restrict__ woT) {
  __shared__ float tile[32][33];
  const int bid = blockIdx.x;
  const int tx = threadIdx.x, ty = threadIdx.y;
  if (bid < 2048) {
    const int tid = ty * 32 + tx;
    const long n = 4096ll * 2048;
    const long stride = 2048ll * 256 * 4;
    for (long i = ((long)bid * 256 + tid) * 4; i < n; i += stride) {
      float4 v = *(const float4*)(x + i);
      union { u16 s[4]; uint2 u; } pk;
      pk.s[0] = f2bf(v.x); pk.s[1] = f2bf(v.y); pk.s[2] = f2bf(v.z); pk.s[3] = f2bf(v.w);
      *(uint2*)(xb + i) = pk.u;
    }
    return;
  }
  const float* W; u16* WT; int K, N, bx, by;
  int r = bid - 2048;
  if (r < 6144)        { W = w_q;   WT = wqT;  K = 2048; N = 3072; bx = r % 96; by = r / 96; }
  else if ((r -= 6144) < 512) { W = w_kvd; WT = wkdT; K = 2048; N = 256;  bx = r % 8;  by = r / 8; }
  else if ((r -= 512) < 768)  { W = w_ku;  WT = wkuT; K = 256;  N = 3072; bx = r % 96; by = r / 96; }
  else if ((r -= 768) < 512)  { W = w_vu;  WT = wvuT; K = 256;  N = 2048; bx = r % 64; by = r / 64; }
  else                 { r -= 512; W = w_o; WT = woT; K = 2048; N = 2048; bx = r % 64; by = r / 64; }
  const int n0 = bx * 32, k0 = by * 32;
#pragma unroll
  for (int i = 0; i < 32; i += 8) tile[ty + i][tx] = W[(long)(k0 + ty + i) * N + n0 + tx];
  __syncthreads();
#pragma unroll
  for (int i = 0; i < 32; i += 8)
    WT[(long)(n0 + ty + i) * K + k0 + tx] = f2bf(tile[tx][ty + i]);
}

// ------------------- fused-rope epilogue helper (q/k layout [row][h*192+d])
__device__ __forceinline__ void epilogue_rope_store(
    u16* __restrict__ C, const int N, const f32x4 (*acc)[4],
    const int m0, const int wr, const int wc, const int cbase_wave,
    const int lrow, const int lg, const bool ropewin,
    const float* __restrict__ freqs, const int sp) {
#pragma unroll
  for (int mi = 0; mi < 4; mi++) {
    const int r0 = m0 + (wr << 6) + (mi << 4) + (lg << 2);
#pragma unroll
    for (int r = 0; r < 4; r++) {
      float v0 = acc[mi][0][r], v1 = acc[mi][1][r];
      float v2 = acc[mi][2][r], v3 = acc[mi][3][r];
      if (ropewin) {
        const int t = (r0 + r) & 2047;
        const float2 cs0 = *(const float2*)&freqs[((long)(sp + t) * 32 + lrow) * 2];
        const float2 cs1 = *(const float2*)&freqs[((long)(sp + t) * 32 + 16 + lrow) * 2];
        const float n0v = v0 * cs0.x - v2 * cs0.y;
        const float n1v = v1 * cs1.x - v3 * cs1.y;
        const float n2v = v2 * cs0.x + v0 * cs0.y;
        const float n3v = v3 * cs1.x + v1 * cs1.y;
        v0 = n0v; v1 = n1v; v2 = n2v; v3 = n3v;
      }
      const long ro = (long)(r0 + r) * N + cbase_wave + lrow;
      C[ro] = f2bf(v0);
      C[ro + 16] = f2bf(v1);
      C[ro + 32] = f2bf(v2);
      C[ro + 48] = f2bf(v3);
    }
  }
}

// --------------------------------------- fused q + kv_down GEMM (shared A=xb)
__global__ __launch_bounds__(256, 4)
void gemm_q_kvd_kernel(const u16* __restrict__ A, const u16* __restrict__ wqT,
                       const u16* __restrict__ wkdT, u16* __restrict__ qb,
                       u16* __restrict__ kvb,
                       const float* __restrict__ freqs, const int* __restrict__ sp_ptr) {
  constexpr int K = 2048;
  const int bid = blockIdx.x;
  const int xcd = bid & 7;
  const int idx = bid >> 3;                 // 0..103
  const int m0 = ((xcd << 2) + (idx & 3)) << 7;
  const int n0raw = (idx >> 2) << 7;        // n-tile 0..25
  const bool is_kv = n0raw >= 3072;
  const u16* BT = is_kv ? (wkdT + (long)(n0raw - 3072) * K) : (wqT + (long)n0raw * K);
  u16* C = is_kv ? kvb : qb;
  const int N = is_kv ? 256 : 3072;
  const int c_base = is_kv ? (n0raw - 3072) : n0raw;
  __shared__ alignas(16) u16 lA[128 * 64];
  __shared__ alignas(16) u16 lB[128 * 64];
  const int tid = threadIdx.x;
  const int w = tid >> 6, l = tid & 63;
  const int wr = w >> 1, wc = w & 1;
  const int lrow = l & 15, lg = l >> 4;
  const int srow = l >> 3, scol = (l & 7) << 3;
  f32x4 acc[4][4] = {};
  for (int kt = 0; kt < K; kt += 64) {
    __syncthreads();
#pragma unroll
    for (int i = 0; i < 4; i++) {
      const int chunk = (w << 2) + i;
      const int row = (chunk << 3) + srow;
      GLD_LDS16(A + (long)(m0 + row) * K + kt + scol, &lA[chunk << 9]);
      GLD_LDS16(BT + (long)row * K + kt + scol, &lB[chunk << 9]);
    }
    __syncthreads();
#pragma unroll
    for (int kk = 0; kk < 2; kk++) {
      bf16x8 af[4], bb[4];
#pragma unroll
      for (int i = 0; i < 4; i++) {
        af[i] = *(const bf16x8*)&lA[((wr << 6) + (i << 4) + lrow) * 64 + (kk << 5) + (lg << 3)];
        bb[i] = *(const bf16x8*)&lB[((wc << 6) + (i << 4) + lrow) * 64 + (kk << 5) + (lg << 3)];
      }
#pragma unroll
      for (int mi = 0; mi < 4; mi++)
#pragma unroll
        for (int ni = 0; ni < 4; ni++)
          acc[mi][ni] = MFMA16(af[mi], bb[ni], acc[mi][ni]);
    }
  }
  const int cbase_wave = c_base + (wc << 6);
  const bool ropewin = (!is_kv) && (cbase_wave % 192 == 128);
  const int sp = sp_ptr[0];
  epilogue_rope_store(C, N, acc, m0, wr, wc, cbase_wave, lrow, lg, ropewin, freqs, sp);
}

// ---------------------------- merged k_up + vT GEMM (both K=256, read kvb)
__global__ __launch_bounds__(256, 4)
void gemm_kup_vt_kernel(const u16* __restrict__ kvb, const u16* __restrict__ wkuT,
                        const u16* __restrict__ wvuT, u16* __restrict__ kb,
                        u16* __restrict__ vTb,
                        const float* __restrict__ freqs, const int* __restrict__ sp_ptr) {
  constexpr int K = 256;
  const int bid = blockIdx.x;
  const u16 *A, *BT;
  u16* C;
  int N, m0, n0;
  bool is_k;
  if (bid < 768) {                          // k-up: 32 m-tiles x 24 n-tiles
    const int xcd = bid & 7, idx = bid >> 3;
    A = kvb; BT = wkuT; C = kb; N = 3072;
    m0 = ((xcd << 2) + (idx & 3)) << 7;
    n0 = (idx >> 2) << 7;
    is_k = true;
  } else {                                  // vT: 2 bz x 16 m x 16 n
    const int r = bid - 768;
    const int xcd = r & 7, idx = r >> 3;
    const int mt = (xcd << 1) + (idx & 1);
    const int rest = idx >> 1;
    const int nt = rest & 15, bz = rest >> 4;
    A = wvuT; BT = kvb + (long)bz * 2048 * 256; C = vTb + (long)bz * 2048 * 2048;
    N = 2048;
    m0 = mt << 7; n0 = nt << 7;
    is_k = false;
  }
  __shared__ alignas(16) u16 lA[128 * 64];
  __shared__ alignas(16) u16 lB[128 * 64];
  const int tid = threadIdx.x;
  const int w = tid >> 6, l = tid & 63;
  const int wr = w >> 1, wc = w & 1;
  const int lrow = l & 15, lg = l >> 4;
  const int srow = l >> 3, scol = (l & 7) << 3;
  f32x4 acc[4][4] = {};
  for (int kt = 0; kt < K; kt += 64) {
    __syncthreads();
#pragma unroll
    for (int i = 0; i < 4; i++) {
      const int chunk = (w << 2) + i;
      const int row = (chunk << 3) + srow;
      GLD_LDS16(A + (long)(m0 + row) * K + kt + scol, &lA[chunk << 9]);
      GLD_LDS16(BT + (long)(n0 + row) * K + kt + scol, &lB[chunk << 9]);
    }
    __syncthreads();
#pragma unroll
    for (int kk = 0; kk < 2; kk++) {
      bf16x8 af[4], bb[4];
#pragma unroll
      for (int i = 0; i < 4; i++) {
        af[i] = *(const bf16x8*)&lA[((wr << 6) + (i << 4) + lrow) * 64 + (kk << 5) + (lg << 3)];
        bb[i] = *(const bf16x8*)&lB[((wc << 6) + (i << 4) + lrow) * 64 + (kk << 5) + (lg << 3)];
      }
#pragma unroll
      for (int mi = 0; mi < 4; mi++)
#pragma unroll
        for (int ni = 0; ni < 4; ni++)
          acc[mi][ni] = MFMA16(af[mi], bb[ni], acc[mi][ni]);
    }
  }
  const int cbase_wave = n0 + (wc << 6);
  const bool ropewin = is_k && (cbase_wave % 192 == 128);
  const int sp = sp_ptr[0];
  epilogue_rope_store(C, N, acc, m0, wr, wc, cbase_wave, lrow, lg, ropewin, freqs, sp);
}

// ---------------------------- out GEMM: out = aob @ woT^T (f32 out), swizzled
__global__ __launch_bounds__(256, 4)
void gemm_out_kernel(const u16* __restrict__ A, const u16* __restrict__ BT,
                     float* __restrict__ C) {
  constexpr int K = 2048, N = 2048;
  const int bid = blockIdx.x;               // 512 = 32 m x 16 n
  const int xcd = bid & 7, idx = bid >> 3;
  const int m0 = ((xcd << 2) + (idx & 3)) << 7;
  const int n0 = (idx >> 2) << 7;
  __shared__ alignas(16) u16 lA[128 * 64];
  __shared__ alignas(16) u16 lB[128 * 64];
  const int tid = threadIdx.x;
  const int w = tid >> 6, l = tid & 63;
  const int wr = w >> 1, wc = w & 1;
  const int lrow = l & 15, lg = l >> 4;
  const int srow = l >> 3, scol = (l & 7) << 3;
  f32x4 acc[4][4] = {};
  for (int kt = 0; kt < K; kt += 64) {
    __syncthreads();
#pragma unroll
    for (int i = 0; i < 4; i++) {
      const int chunk = (w << 2) + i;
      const int row = (chunk << 3) + srow;
      GLD_LDS16(A + (long)(m0 + row) * K + kt + scol, &lA[chunk << 9]);
      GLD_LDS16(BT + (long)(n0 + row) * K + kt + scol, &lB[chunk << 9]);
    }
    __syncthreads();
#pragma unroll
    for (int kk = 0; kk < 2; kk++) {
      bf16x8 af[4], bb[4];
#pragma unroll
      for (int i = 0; i < 4; i++) {
        af[i] = *(const bf16x8*)&lA[((wr << 6) + (i << 4) + lrow) * 64 + (kk << 5) + (lg << 3)];
        bb[i] = *(const bf16x8*)&lB[((wc << 6) + (i << 4) + lrow) * 64 + (kk << 5) + (lg << 3)];
      }
#pragma unroll
      for (int mi = 0; mi < 4; mi++)
#pragma unroll
        for (int ni = 0; ni < 4; ni++)
          acc[mi][ni] = MFMA16(af[mi], bb[ni], acc[mi][ni]);
    }
  }
#pragma unroll
  for (int mi = 0; mi < 4; mi++) {
    const int r0 = m0 + (wr << 6) + (mi << 4) + (lg << 2);
#pragma unroll
    for (int ni = 0; ni < 4; ni++) {
      const int c0 = n0 + (wc << 6) + (ni << 4) + lrow;
#pragma unroll
      for (int r = 0; r < 4; r++)
        C[(long)(r0 + r) * N + c0] = acc[mi][ni][r];
    }
  }
}

// --------------------------------------------------- flash attention (paired)
// Round-18 best (DMA-swizzled staging, conflicts=0) + VALU diet v2 (isolated):
// (1) causal mask SPECIALIZED away on interior tiles (template<MASK>; only
//     diagonal tiles pay the 64 cmp+cndmask), (2) native scalar bf16 cast in
//     the P-store (exp stays __expf — round-15 showed exp2f was the regressor).

__device__ __forceinline__ const u16* kaddr(const u16* Kl, int tb, int lrow, int jr_sw) {
  return &Kl[((tb << 4) + lrow) * 192 + (jr_sw << 3)];
}

template <bool MASK>
__device__ __forceinline__ void attn_tile_step(
    const bf16x8* __restrict__ qf, f32x4* __restrict__ o, float* __restrict__ l_part,
    const int qrb, const int t0,
    const u16* __restrict__ Kl, const u16* __restrict__ Vl,
    u16* __restrict__ pw, const int lrow, const int lg) {
  constexpr float SCALE = 0.07216878364870323f;  // 1/sqrt(192)
  const int ks = lrow & 7;
  f32x4 s[4];
  __builtin_amdgcn_s_setprio(1);
#pragma unroll
  for (int tb = 0; tb < 4; tb++) {
    f32x4 a = {};
#pragma unroll
    for (int kb = 0; kb < 6; kb++) {
      const int jr = (kb << 2) + lg;
      const int jr_sw = (jr & 24) | ((jr & 7) ^ ks);
      bf16x8 kf = *(const bf16x8*)kaddr(Kl, tb, lrow, jr_sw);
      a = MFMA16(qf[kb], kf, a);
    }
    s[tb] = a;
  }
  __builtin_amdgcn_s_setprio(0);
#pragma unroll
  for (int tb = 0; tb < 4; tb++) {
    const int tt = t0 + (tb << 4) + lrow;
#pragma unroll
    for (int r = 0; r < 4; r++) {
      float p = __expf(s[tb][r] * SCALE);
      if constexpr (MASK) {
        const int qrow = qrb + (lg << 2) + r;
        p = (tt <= qrow) ? p : 0.f;
      }
      s[tb][r] = p;
      l_part[r] += p;
    }
  }
#pragma unroll
  for (int tb = 0; tb < 4; tb++)
#pragma unroll
    for (int r = 0; r < 4; r++)
      pw[((lg << 2) + r) * 68 + (tb << 4) + lrow] = f2bf_n(s[tb][r]);
  bf16x8 pf0 = *(const bf16x8*)&pw[lrow * 68 + (lg << 3)];
  bf16x8 pf1 = *(const bf16x8*)&pw[lrow * 68 + 32 + (lg << 3)];
  const int vc0 = (lg ^ ks) << 3, vc1 = ((4 + lg) ^ ks) << 3;
  __builtin_amdgcn_s_setprio(1);
#pragma unroll
  for (int db = 0; db < 8; db++) {
    const int vrow = ((db << 4) + lrow) << 6;  // *64
    bf16x8 v0 = *(const bf16x8*)&Vl[vrow + vc0];
    bf16x8 v1 = *(const bf16x8*)&Vl[vrow + vc1];
    o[db] = MFMA16(pf0, v0, o[db]);
    o[db] = MFMA16(pf1, v1, o[db]);
  }
  __builtin_amdgcn_s_setprio(0);
}

template <bool MASKA>
__device__ __forceinline__ void attn_tile_step2(
    const bf16x8* __restrict__ qfA, const bf16x8* __restrict__ qfB,
    f32x4* __restrict__ oA, f32x4* __restrict__ oB,
    float* __restrict__ lpA, float* __restrict__ lpB,
    const int qrbA, const int t0,
    const u16* __restrict__ Kl, const u16* __restrict__ Vl,
    u16* __restrict__ pwA, u16* __restrict__ pwB, const int lrow, const int lg) {
  constexpr float SCALE = 0.07216878364870323f;  // 1/sqrt(192)
  const int ks = lrow & 7;
  f32x4 sA[4], sB[4];
  __builtin_amdgcn_s_setprio(1);
#pragma unroll
  for (int tb = 0; tb < 4; tb++) {
    f32x4 a = {}, bq = {};
#pragma unroll
    for (int kb = 0; kb < 6; kb++) {
      const int jr = (kb << 2) + lg;
      const int jr_sw = (jr & 24) | ((jr & 7) ^ ks);
      bf16x8 kf = *(const bf16x8*)kaddr(Kl, tb, lrow, jr_sw);
      a = MFMA16(qfA[kb], kf, a);
      bq = MFMA16(qfB[kb], kf, bq);
    }
    sA[tb] = a;
    sB[tb] = bq;
  }
  __builtin_amdgcn_s_setprio(0);
#pragma unroll
  for (int tb = 0; tb < 4; tb++) {
    const int tt = t0 + (tb << 4) + lrow;
#pragma unroll
    for (int r = 0; r < 4; r++) {
      float pA = __expf(sA[tb][r] * SCALE);
      if constexpr (MASKA) {
        const int qrowA = qrbA + (lg << 2) + r;
        pA = (tt <= qrowA) ? pA : 0.f;
      }
      sA[tb][r] = pA;
      lpA[r] += pA;
      float pB = __expf(sB[tb][r] * SCALE);  // B interior in the fused range
      sB[tb][r] = pB;
      lpB[r] += pB;
    }
  }
#pragma unroll
  for (int tb = 0; tb < 4; tb++)
#pragma unroll
    for (int r = 0; r < 4; r++) {
      pwA[((lg << 2) + r) * 68 + (tb << 4) + lrow] = f2bf_n(sA[tb][r]);
      pwB[((lg << 2) + r) * 68 + (tb << 4) + lrow] = f2bf_n(sB[tb][r]);
    }
  bf16x8 pfA0 = *(const bf16x8*)&pwA[lrow * 68 + (lg << 3)];
  bf16x8 pfA1 = *(const bf16x8*)&pwA[lrow * 68 + 32 + (lg << 3)];
  bf16x8 pfB0 = *(const bf16x8*)&pwB[lrow * 68 + (lg << 3)];
  bf16x8 pfB1 = *(const bf16x8*)&pwB[lrow * 68 + 32 + (lg << 3)];
  const int vc0 = (lg ^ ks) << 3, vc1 = ((4 + lg) ^ ks) << 3;
  __builtin_amdgcn_s_setprio(1);
#pragma unroll
  for (int db = 0; db < 8; db++) {
    const int vrow = ((db << 4) + lrow) << 6;  // *64
    bf16x8 v0 = *(const bf16x8*)&Vl[vrow + vc0];
    bf16x8 v1 = *(const bf16x8*)&Vl[vrow + vc1];
    oA[db] = MFMA16(pfA0, v0, oA[db]);
    oB[db] = MFMA16(pfB0, v0, oB[db]);
    oA[db] = MFMA16(pfA1, v1, oA[db]);
    oB[db] = MFMA16(pfB1, v1, oB[db]);
  }
  __builtin_amdgcn_s_setprio(0);
}

__device__ __forceinline__ void attn_write(
    u16* __restrict__ ob, const f32x4* __restrict__ o, const float* __restrict__ l_part,
    const int lrow, const int lg) {
#pragma unroll
  for (int r = 0; r < 4; r++) {
    float l = l_part[r];
#pragma unroll
    for (int d = 1; d < 16; d <<= 1) l += __shfl_xor(l, d);
    const float inv = 1.f / l;
#pragma unroll
    for (int db = 0; db < 8; db++)
      ob[(long)((lg << 2) + r) * 2048 + (db << 4) + lrow] = f2bf(o[db][r] * inv);
  }
}

// Triangle-paired causal flash attention, XCD-swizzled (bh%8 == bid%8),
// 512 blocks x 256 threads. DMA-swizzled K/V staging (0 bank conflicts).
// Mask only on diagonal tiles: A-diag at t0==tEndA (fused), B-diag at t0==tEndB.
__global__ __launch_bounds__(256, 2)
void attn_kernel(const u16* __restrict__ q, const u16* __restrict__ k,
                 const u16* __restrict__ vT, u16* __restrict__ out) {
  const int bid = blockIdx.x;
  const int xcd = bid & 7;
  const int rest = bid >> 3;
  const int pair = rest & 15;
  const int bh = ((rest >> 4) << 3) | xcd;   // bh % 8 == XCD
  const int b = bh >> 4, h = bh & 15;
  const int tid = threadIdx.x, w = tid >> 6, l = tid & 63;
  const int lrow = l & 15, lg = l >> 4;
  const int qtA = pair, qtB = 31 - pair;
  const int qrbA = (qtA << 6) + (w << 4);
  const int qrbB = (qtB << 6) + (w << 4);
  __shared__ alignas(16) u16 Kl[64 * 192];      // linear [t][192]  (24.6KB)
  __shared__ alignas(16) u16 Vl[128 * 64];      // linear [d][64]   (16.4KB)
  __shared__ alignas(16) u16 Pl[4][2][16 * 68]; // per-wave P x{A,B}(17.4KB)

  bf16x8 qfA[6], qfB[6];
  {
    const u16* qbA = q + ((long)b * 2048 + qrbA + lrow) * 3072 + h * 192;
    const u16* qbB = q + ((long)b * 2048 + qrbB + lrow) * 3072 + h * 192;
#pragma unroll
    for (int kb = 0; kb < 6; kb++) {
      qfA[kb] = *(const bf16x8*)&qbA[(kb << 5) + (lg << 3)];
      qfB[kb] = *(const bf16x8*)&qbB[(kb << 5) + (lg << 3)];
    }
  }
  f32x4 oA[8] = {}, oB[8] = {};
  float lA[4] = {}, lB[4] = {};

  const u16* kbh = k + (long)b * 2048 * 3072 + h * 192;
  const u16* vbh = vT + ((long)b * 2048 + h * 128) * 2048;
  const int tEndA = qtA << 6, tEndB = qtB << 6;

  int krow_[6], kcol_[6], vrow_[4], vcol_[4];
#pragma unroll
  for (int i = 0; i < 6; i++) {
    const int c = (i << 8) + tid;
    krow_[i] = c / 24;
    const int j = c % 24;
    kcol_[i] = ((j & 24) | ((j & 7) ^ (krow_[i] & 7))) << 3;
  }
#pragma unroll
  for (int i = 0; i < 4; i++) {
    const int c = (i << 8) + tid;
    vrow_[i] = c >> 3;
    vcol_[i] = ((c & 7) ^ (vrow_[i] & 7)) << 3;
  }
  const int wbase = (tid & ~63) << 3;  // wave's chunk base * 8 u16

  for (int t0 = 0; t0 <= tEndB; t0 += 64) {
    __syncthreads();
#pragma unroll
    for (int i = 0; i < 6; i++)
      GLD_LDS16(kbh + (long)(t0 + krow_[i]) * 3072 + kcol_[i], &Kl[(i << 11) + wbase]);
#pragma unroll
    for (int i = 0; i < 4; i++)
      GLD_LDS16(vbh + (long)vrow_[i] * 2048 + t0 + vcol_[i], &Vl[(i << 11) + wbase]);
    __syncthreads();
    if (t0 < tEndA)
      attn_tile_step2<false>(qfA, qfB, oA, oB, lA, lB, qrbA, t0, Kl, Vl,
                             &Pl[w][0][0], &Pl[w][1][0], lrow, lg);
    else if (t0 == tEndA)
      attn_tile_step2<true>(qfA, qfB, oA, oB, lA, lB, qrbA, t0, Kl, Vl,
                            &Pl[w][0][0], &Pl[w][1][0], lrow, lg);
    else if (t0 < tEndB)
      attn_tile_step<false>(qfB, oB, lB, qrbB, t0, Kl, Vl, &Pl[w][1][0], lrow, lg);
    else
      attn_tile_step<true>(qfB, oB, lB, qrbB, t0, Kl, Vl, &Pl[w][1][0], lrow, lg);
  }
  attn_write(out + ((long)b * 2048 + qrbA) * 2048 + (h << 7), oA, lA, lrow, lg);
  attn_write(out + ((long)b * 2048 + qrbB) * 2048 + (h << 7), oB, lB, lrow, lg);
}

// ----------------------------------------------------------------- launch
extern "C" void kernel_launch(void* const* d_in, const int* in_sizes, int n_in,
                              void* d_out, int out_size, void* d_ws, size_t ws_size,
                              hipStream_t stream) {
  const float* x = (const float*)d_in[0];
  const float* fcis = (const float*)d_in[1];
  const float* w_q = (const float*)d_in[2];
  const float* w_kvd = (const float*)d_in[3];
  const float* w_ku = (const float*)d_in[4];
  const float* w_vu = (const float*)d_in[5];
  const float* w_o = (const float*)d_in[6];
  const int* start_pos = (const int*)d_in[7];
  float* out = (float*)d_out;

  char* p = (char*)d_ws;
  auto alloc = [&](long bytes) -> char* {
    char* r = p;
    p += (bytes + 255) & ~255ll;
    return r;
  };
  u16* xb = (u16*)alloc(4096ll * 2048 * 2);    // x bf16
  u16* wqT = (u16*)alloc(3072ll * 2048 * 2);   // w_q^T
  u16* wkdT = (u16*)alloc(256ll * 2048 * 2);   // w_kv_down^T
  u16* wkuT = (u16*)alloc(3072ll * 256 * 2);   // w_k_up^T
  u16* wvuT = (u16*)alloc(2048ll * 256 * 2);   // w_v_up^T
  u16* woT = (u16*)alloc(2048ll * 2048 * 2);   // w_o^T
  u16* qb = (u16*)alloc(4096ll * 3072 * 2);    // q (rope fused in epilogue)
  u16* kvb = (u16*)alloc(4096ll * 256 * 2);    // kv
  u16* kb = (u16*)alloc(4096ll * 3072 * 2);    // k (rope fused in epilogue)
  u16* aob = (u16*)alloc(4096ll * 2048 * 2);   // attention out
  u16* vTb = xb;  // alias: x-bf16 is dead before the vT GEMM runs (stream order)

  // merged conv + all 5 weight transposes: 14080 blocks of (32,8)
  prep_kernel<<<14080, dim3(32, 8), 0, stream>>>(x, xb, w_q, wqT, w_kvd, wkdT,
                                                 w_ku, wkuT, w_vu, wvuT, w_o, woT);
  // fused q = x@w_q (+RoPE) and kv = x@w_kv_down; XCD m-band swizzled
  gemm_q_kvd_kernel<<<832, 256, 0, stream>>>(xb, wqT, wkdT, qb, kvb, fcis, start_pos);
  // merged k = kv@w_k_up (+RoPE) + vT = w_v_up^T@kv^T; XCD m-band swizzled
  gemm_kup_vt_kernel<<<1280, 256, 0, stream>>>(kvb, wkuT, wvuT, kb, vTb, fcis, start_pos);
  // XCD-swizzled triangle-paired attention: 512 blocks x 256 threads
  attn_kernel<<<512, 256, 0, stream>>>(qb, kb, vTb, aob);
  // out = attn_out @ w_o -> f32; XCD m-band swizzled
  gemm_out_kernel<<<512, 256, 0, stream>>>(aob, woT, out);
}